// Round 11
// baseline (468.055 us; speedup 1.0000x reference)
//
#include <hip/hip_runtime.h>

#define NNODES 50000
#define NEDGES 800000
#define ET (NEDGES + NNODES)   // 850000 edges incl. self loops
#define HEADS 4

typedef __attribute__((ext_vector_type(8))) short bf16x8;
typedef __attribute__((ext_vector_type(4))) float f32x4;

#define EXP2F(x) __builtin_amdgcn_exp2f(x)   // v_exp_f32; __exp2f collides with glibc

// async global->LDS, 16B per lane (m97 recipe). Dest must be lane-linear.
#define GLOAD16(g, l) __builtin_amdgcn_global_load_lds(                      \
    (const __attribute__((address_space(1))) unsigned int*)(g),              \
    (__attribute__((address_space(3))) unsigned int*)(l), 16, 0, 0)

__device__ inline unsigned short f2bf(float f) {
  union { float f; unsigned int i; } c; c.f = f;
  unsigned int b = c.i + 0x7fffu + ((c.i >> 16) & 1u);   // RTN-even
  return (unsigned short)(b >> 16);
}
__device__ inline float4 b4tof(uint2 r) {
  float4 f;
  union { unsigned int i; float v; } c;
  c.i = r.x << 16;          f.x = c.v;
  c.i = r.x & 0xffff0000u;  f.y = c.v;
  c.i = r.y << 16;          f.z = c.v;
  c.i = r.y & 0xffff0000u;  f.w = c.v;
  return f;
}

// ---------------- CSR build (by dst) ----------------

__global__ void k_hist(const int* __restrict__ ei, int* __restrict__ deg) {
  int i = blockIdx.x * blockDim.x + threadIdx.x;
  if (i >= ET) return;
  int dst = (i < NEDGES) ? ei[NEDGES + i] : (i - NEDGES);
  atomicAdd(&deg[dst], 1);
}

__global__ void k_scan1(const int* __restrict__ deg, int* __restrict__ part,
                        int* __restrict__ bsum, int n) {
  __shared__ int s[256];
  int tid = threadIdx.x;
  int i = blockIdx.x * 256 + tid;
  int v = (i < n) ? deg[i] : 0;
  s[tid] = v;
  __syncthreads();
  for (int off = 1; off < 256; off <<= 1) {
    int t = (tid >= off) ? s[tid - off] : 0;
    __syncthreads();
    s[tid] += t;
    __syncthreads();
  }
  if (i < n) part[i] = s[tid] - v;
  if (tid == 255) bsum[blockIdx.x] = s[255];
}

__global__ void k_scan2(int* bsum, int nb) {
  __shared__ int s[256];
  int t = threadIdx.x;
  int v = (t < nb) ? bsum[t] : 0;
  s[t] = v;
  __syncthreads();
  for (int off = 1; off < 256; off <<= 1) {
    int tv = (t >= off) ? s[t - off] : 0;
    __syncthreads();
    s[t] += tv;
    __syncthreads();
  }
  if (t < nb) bsum[t] = s[t] - v;
}

__global__ void k_scan3(const int* __restrict__ part, const int* __restrict__ bsum,
                        int* __restrict__ rowstart, int* __restrict__ cursor,
                        int n, int total) {
  int i = blockIdx.x * blockDim.x + threadIdx.x;
  if (i < n) {
    int v = part[i] + bsum[i >> 8];
    rowstart[i] = v;
    cursor[i] = v;
  }
  if (i == n) rowstart[n] = total;
}

__global__ void k_scatter(const int* __restrict__ ei, int* __restrict__ cursor,
                          int* __restrict__ csrsrc) {
  int i = blockIdx.x * blockDim.x + threadIdx.x;
  if (i >= ET) return;
  int src, dst;
  if (i < NEDGES) { src = ei[i]; dst = ei[NEDGES + i]; }
  else            { src = dst = i - NEDGES; }
  int pos = atomicAdd(&cursor[dst], 1);
  csrsrc[pos] = src;
}

// ---------------- casts ----------------

__global__ void k_cast_bf16(const float* __restrict__ in, unsigned short* __restrict__ out, int n4) {
  int i = blockIdx.x * blockDim.x + threadIdx.x;
  if (i >= n4) return;
  float4 v = ((const float4*)in)[i];
  ushort4 o;
  o.x = f2bf(v.x); o.y = f2bf(v.y); o.z = f2bf(v.z); o.w = f2bf(v.w);
  ((ushort4*)out)[i] = o;
}

// transpose-cast via 32x32 LDS tiles: W[K][N] f32 -> T[(n+noff)][K] bf16.
// blockIdx.y selects weight; both reads and writes fully coalesced.
__global__ __launch_bounds__(256) void k_castw_all(
    const float* __restrict__ W1l, const float* __restrict__ W1r,
    const float* __restrict__ W2l, const float* __restrict__ W2r,
    unsigned short* __restrict__ w1t, unsigned short* __restrict__ w2t) {
  __shared__ float tile[32][33];
  int which = blockIdx.y;
  const float* W;
  unsigned short* T;
  int K, N, noff;
  if (which == 0)      { W = W1l; T = w1t; K = 512; N = 256; noff = 0; }
  else if (which == 1) { W = W1r; T = w1t; K = 512; N = 256; noff = 256; }
  else if (which == 2) { W = W2l; T = w2t; K = 256; N = 512; noff = 0; }
  else                 { W = W2r; T = w2t; K = 256; N = 512; noff = 512; }
  int tpr = N >> 5;                        // tiles per K-row
  int tk = (blockIdx.x / tpr) << 5;
  int tn = (blockIdx.x % tpr) << 5;
  int c = threadIdx.x & 31, r = threadIdx.x >> 5;  // 32 x 8
#pragma unroll
  for (int rr = 0; rr < 32; rr += 8)
    tile[r + rr][c] = W[(size_t)(tk + r + rr) * N + tn + c];
  __syncthreads();
#pragma unroll
  for (int rr = 0; rr < 32; rr += 8)
    T[(size_t)(tn + r + rr + noff) * K + tk + c] = f2bf(tile[c][r + rr]);
}

// ---------------- bf16 MFMA GEMM, 2-phase dbuf (T3-minimum, m248v2 pattern) ----
// C = A(M,K) * Bt(N,K)^T + bias. 128x128 tile, BK=32, linear LDS, GLOAD16 staging.

__global__ __launch_bounds__(256) void k_gemm(
    const unsigned short* __restrict__ A, const unsigned short* __restrict__ Bt,
    const float* __restrict__ bL, const float* __restrict__ bR, int nsplit,
    unsigned short* __restrict__ C, int M, int K, int N) {
  __shared__ unsigned short As[2][128 * 32];   // 2 x 8 KB
  __shared__ unsigned short Bs[2][128 * 32];
  int tid = threadIdx.x;
  int lane = tid & 63, wave = tid >> 6;
  int wr = (wave >> 1) * 64, wc = (wave & 1) * 64;
  int row0 = blockIdx.x * 128, col0 = blockIdx.y * 128;
  int fr = lane & 15, fq = lane >> 4;
  int sr = tid >> 2, sc = (tid & 3) * 8;

  const unsigned short* ga0 = &A[(size_t)(row0 + sr) * K + sc];
  const unsigned short* ga1 = &A[(size_t)(row0 + sr + 64) * K + sc];
  const unsigned short* gb0 = &Bt[(size_t)(col0 + sr) * K + sc];
  const unsigned short* gb1 = &Bt[(size_t)(col0 + sr + 64) * K + sc];

  f32x4 acc[4][4] = {};
  const int NT = K >> 5;

  // prologue: stage tile 0 into buf 0
  GLOAD16(ga0, &As[0][tid * 8]);
  GLOAD16(ga1, &As[0][2048 + tid * 8]);
  GLOAD16(gb0, &Bs[0][tid * 8]);
  GLOAD16(gb1, &Bs[0][2048 + tid * 8]);
  asm volatile("s_waitcnt vmcnt(0)" ::: "memory");
  __builtin_amdgcn_s_barrier();

  int cur = 0;
  for (int t = 0; t < NT; ++t) {
    if (t + 1 < NT) {            // issue next tile BEFORE computing current
      int k0 = (t + 1) << 5;
      GLOAD16(ga0 + k0, &As[cur ^ 1][tid * 8]);
      GLOAD16(ga1 + k0, &As[cur ^ 1][2048 + tid * 8]);
      GLOAD16(gb0 + k0, &Bs[cur ^ 1][tid * 8]);
      GLOAD16(gb1 + k0, &Bs[cur ^ 1][2048 + tid * 8]);
    }
    bf16x8 af[4], bfr[4];
#pragma unroll
    for (int m = 0; m < 4; ++m)
      af[m] = *(const bf16x8*)&As[cur][(wr + m * 16 + fr) * 32 + fq * 8];
#pragma unroll
    for (int n = 0; n < 4; ++n)
      bfr[n] = *(const bf16x8*)&Bs[cur][(wc + n * 16 + fr) * 32 + fq * 8];
#pragma unroll
    for (int m = 0; m < 4; ++m)
#pragma unroll
      for (int n = 0; n < 4; ++n)
        acc[m][n] = __builtin_amdgcn_mfma_f32_16x16x32_bf16(af[m], bfr[n], acc[m][n], 0, 0, 0);
    asm volatile("s_waitcnt vmcnt(0)" ::: "memory");  // next tile landed
    __builtin_amdgcn_s_barrier();                     // reads done + tile published
    cur ^= 1;
  }

#pragma unroll
  for (int m = 0; m < 4; ++m) {
#pragma unroll
    for (int n = 0; n < 4; ++n) {
      int col = col0 + wc + n * 16 + fr;
      float bv = (col < nsplit) ? bL[col] : bR[col - nsplit];
#pragma unroll
      for (int j = 0; j < 4; ++j) {
        int row = row0 + wr + m * 16 + fq * 4 + j;
        if (row < M) C[(size_t)row * N + col] = f2bf(acc[m][n][j] + bv);
      }
    }
  }
}

// ---------------- fused score + softmax + aggregate (bf16 inputs) ----------------
// One wave per dst; 16 lanes per head; lane covers CHL=CQ*4 CONTIGUOUS channels
// (CQ=1: uint2 8B gather, CQ=2: uint4 16B gather - single load per edge).
// exp2-domain, no max tracking (|p|<~15 by construction). 4-edge unroll.

template <int CQ>
__device__ inline void load_row(const unsigned short* p, float4* xv) {
  if constexpr (CQ == 1) {
    xv[0] = b4tof(*(const uint2*)p);
  } else {
    uint4 r = *(const uint4*)p;
    xv[0] = b4tof(make_uint2(r.x, r.y));
    xv[1] = b4tof(make_uint2(r.z, r.w));
  }
}

template <int CQ>
__device__ inline float edge_score(const float4* xv, const float4* xrv, const float4* attv) {
  float p = 0.f;
#pragma unroll
  for (int q = 0; q < CQ; ++q) {
    float s;
    s = xv[q].x + xrv[q].x; p = fmaf(attv[q].x, fmaxf(s, 0.2f * s), p);
    s = xv[q].y + xrv[q].y; p = fmaf(attv[q].y, fmaxf(s, 0.2f * s), p);
    s = xv[q].z + xrv[q].z; p = fmaf(attv[q].z, fmaxf(s, 0.2f * s), p);
    s = xv[q].w + xrv[q].w; p = fmaf(attv[q].w, fmaxf(s, 0.2f * s), p);
  }
  return p;
}

template <int CQ, int MODE, int STR>
__global__ __launch_bounds__(256) void k_fused(
    const int* __restrict__ rowstart, const int* __restrict__ csrsrc,
    const unsigned short* __restrict__ xlr,
    const float* __restrict__ att, const float* __restrict__ bias,
    void* __restrict__ outp) {
  const int C = CQ * 64;
  const int CHL = CQ * 4;            // contiguous channels per lane
  int dst = (blockIdx.x * blockDim.x + threadIdx.x) >> 6;
  int lane = threadIdx.x & 63;
  if (dst >= NNODES) return;
  int h = lane >> 4;
  int l = lane & 15;
  const int choff = h * C + l * CHL;

  float4 xrv[CQ], attv[CQ];
  load_row<CQ>(&xlr[(size_t)dst * STR + STR / 2 + choff], xrv);
#pragma unroll
  for (int q = 0; q < CQ; ++q) {
    float4 a = *(const float4*)&att[choff + q * 4];
    a.x *= 1.44269504f; a.y *= 1.44269504f;
    a.z *= 1.44269504f; a.w *= 1.44269504f;
    attv[q] = a;
  }

  int rs = __builtin_amdgcn_readfirstlane(rowstart[dst]);
  int re = __builtin_amdgcn_readfirstlane(rowstart[dst + 1]);

  float den = 0.f;
  float4 acc[CQ];
#pragma unroll
  for (int q = 0; q < CQ; ++q) acc[q] = make_float4(0.f, 0.f, 0.f, 0.f);

  int i = rs;
  for (; i + 4 <= re; i += 4) {
    int s0 = csrsrc[i + 0];
    int s1 = csrsrc[i + 1];
    int s2 = csrsrc[i + 2];
    int s3 = csrsrc[i + 3];
    float4 x0[CQ], x1[CQ], x2[CQ], x3[CQ];
    load_row<CQ>(&xlr[(unsigned)s0 * (unsigned)STR + choff], x0);
    load_row<CQ>(&xlr[(unsigned)s1 * (unsigned)STR + choff], x1);
    load_row<CQ>(&xlr[(unsigned)s2 * (unsigned)STR + choff], x2);
    load_row<CQ>(&xlr[(unsigned)s3 * (unsigned)STR + choff], x3);
    float p0 = edge_score<CQ>(x0, xrv, attv);
    float p1 = edge_score<CQ>(x1, xrv, attv);
    float p2 = edge_score<CQ>(x2, xrv, attv);
    float p3 = edge_score<CQ>(x3, xrv, attv);
#pragma unroll
    for (int d = 1; d <= 8; d <<= 1) {
      p0 += __shfl_xor(p0, d);
      p1 += __shfl_xor(p1, d);
      p2 += __shfl_xor(p2, d);
      p3 += __shfl_xor(p3, d);
    }
    float w0 = EXP2F(p0), w1 = EXP2F(p1), w2 = EXP2F(p2), w3 = EXP2F(p3);
    den += (w0 + w1) + (w2 + w3);
#pragma unroll
    for (int q = 0; q < CQ; ++q) {
      acc[q].x = fmaf(w0, x0[q].x, fmaf(w1, x1[q].x, fmaf(w2, x2[q].x, fmaf(w3, x3[q].x, acc[q].x))));
      acc[q].y = fmaf(w0, x0[q].y, fmaf(w1, x1[q].y, fmaf(w2, x2[q].y, fmaf(w3, x3[q].y, acc[q].y))));
      acc[q].z = fmaf(w0, x0[q].z, fmaf(w1, x1[q].z, fmaf(w2, x2[q].z, fmaf(w3, x3[q].z, acc[q].z))));
      acc[q].w = fmaf(w0, x0[q].w, fmaf(w1, x1[q].w, fmaf(w2, x2[q].w, fmaf(w3, x3[q].w, acc[q].w))));
    }
  }
  for (; i < re; ++i) {
    int s0 = csrsrc[i];
    float4 x0[CQ];
    load_row<CQ>(&xlr[(unsigned)s0 * (unsigned)STR + choff], x0);
    float p0 = edge_score<CQ>(x0, xrv, attv);
#pragma unroll
    for (int d = 1; d <= 8; d <<= 1) p0 += __shfl_xor(p0, d);
    float w0 = EXP2F(p0);
    den += w0;
#pragma unroll
    for (int q = 0; q < CQ; ++q) {
      acc[q].x = fmaf(w0, x0[q].x, acc[q].x);
      acc[q].y = fmaf(w0, x0[q].y, acc[q].y);
      acc[q].z = fmaf(w0, x0[q].z, acc[q].z);
      acc[q].w = fmaf(w0, x0[q].w, acc[q].w);
    }
  }

  float inv = 1.f / (den + 1e-16f);

  if (MODE == 0) {
    unsigned short* out = (unsigned short*)outp;
#pragma unroll
    for (int q = 0; q < CQ; ++q) {
      const float4 bv = *(const float4*)&bias[choff + q * 4];
      ushort4 o;
      o.x = f2bf(fmaxf(acc[q].x * inv + bv.x, 0.f));
      o.y = f2bf(fmaxf(acc[q].y * inv + bv.y, 0.f));
      o.z = f2bf(fmaxf(acc[q].z * inv + bv.z, 0.f));
      o.w = f2bf(fmaxf(acc[q].w * inv + bv.w, 0.f));
      *(ushort4*)&out[(size_t)dst * (HEADS * C) + choff + q * 4] = o;
    }
  } else {
    float* out = (float*)outp;
    float r[CQ][4];
#pragma unroll
    for (int q = 0; q < CQ; ++q) {
      r[q][0] = acc[q].x * inv; r[q][1] = acc[q].y * inv;
      r[q][2] = acc[q].z * inv; r[q][3] = acc[q].w * inv;
    }
#pragma unroll
    for (int q = 0; q < CQ; ++q)
#pragma unroll
      for (int j = 0; j < 4; ++j) {
        r[q][j] += __shfl_xor(r[q][j], 16);   // sum across heads
        r[q][j] += __shfl_xor(r[q][j], 32);
      }
    if (lane < 16) {
#pragma unroll
      for (int q = 0; q < CQ; ++q) {
        int c = lane * CHL + q * 4;
        float4 o;
        o.x = r[q][0] * 0.25f + bias[c + 0];
        o.y = r[q][1] * 0.25f + bias[c + 1];
        o.z = r[q][2] * 0.25f + bias[c + 2];
        o.w = r[q][3] * 0.25f + bias[c + 3];
        *(float4*)&out[(size_t)dst * C + c] = o;
      }
    }
  }
}

// ---------------- orchestration ----------------

extern "C" void kernel_launch(void* const* d_in, const int* in_sizes, int n_in,
                              void* d_out, int out_size, void* d_ws, size_t ws_size,
                              hipStream_t stream) {
  (void)in_sizes; (void)n_in; (void)out_size; (void)ws_size;
  const float* x     = (const float*)d_in[0];
  const int*   ei    = (const int*)d_in[1];
  const float* W1l   = (const float*)d_in[2];
  const float* b1l   = (const float*)d_in[3];
  const float* W1r   = (const float*)d_in[4];
  const float* b1r   = (const float*)d_in[5];
  const float* att1  = (const float*)d_in[6];
  const float* bias1 = (const float*)d_in[7];
  const float* W2l   = (const float*)d_in[8];
  const float* b2l   = (const float*)d_in[9];
  const float* W2r   = (const float*)d_in[10];
  const float* b2r   = (const float*)d_in[11];
  const float* att2  = (const float*)d_in[12];
  const float* bias2 = (const float*)d_in[13];
  float* out = (float*)d_out;

  char* ws = (char*)d_ws;
  size_t off = 0;
  auto alloc = [&](size_t bytes) {
    char* p = ws + off;
    off = (off + bytes + 255) & ~(size_t)255;
    return p;
  };
  int*  deg      = (int*)alloc((size_t)NNODES * 4);
  int*  part     = (int*)alloc((size_t)NNODES * 4);
  int*  bsum     = (int*)alloc(256 * 4);
  int*  rowstart = (int*)alloc((size_t)(NNODES + 1) * 4);
  int*  cursor   = (int*)alloc((size_t)NNODES * 4);
  int*  csrsrc   = (int*)alloc((size_t)ET * 4);
  unsigned short* xb   = (unsigned short*)alloc((size_t)NNODES * 512 * 2);
  unsigned short* w1t  = (unsigned short*)alloc((size_t)512 * 512 * 2);
  unsigned short* w2t  = (unsigned short*)alloc((size_t)1024 * 256 * 2);
  unsigned short* xlr1 = (unsigned short*)alloc((size_t)NNODES * 512 * 2);
  unsigned short* hbuf = (unsigned short*)alloc((size_t)NNODES * 256 * 2);
  unsigned short* xlr2 = (unsigned short*)alloc((size_t)NNODES * 1024 * 2);
  (void)alloc(64 * 1024);   // tail pad for GEMM A-row overrun reads

  // CSR build
  (void)hipMemsetAsync(deg, 0, (size_t)NNODES * 4, stream);
  k_hist<<<(ET + 255) / 256, 256, 0, stream>>>(ei, deg);
  int nb = (NNODES + 255) / 256;
  k_scan1<<<nb, 256, 0, stream>>>(deg, part, bsum, NNODES);
  k_scan2<<<1, 256, 0, stream>>>(bsum, nb);
  k_scan3<<<(NNODES + 256) / 256, 256, 0, stream>>>(part, bsum, rowstart, cursor, NNODES, ET);
  k_scatter<<<(ET + 255) / 256, 256, 0, stream>>>(ei, cursor, csrsrc);

  // casts
  k_cast_bf16<<<(NNODES * 512 / 4 + 255) / 256, 256, 0, stream>>>(x, xb, NNODES * 512 / 4);
  k_castw_all<<<dim3(128, 4), 256, 0, stream>>>(W1l, W1r, W2l, W2r, w1t, w2t);

  const int gridM = (NNODES + 127) / 128;   // 391
  const int gridFused = (NNODES + 3) / 4;   // 4 waves/block

  // Layer 1: combined [W1l|W1r], K=512, N=512
  k_gemm<<<dim3(gridM, 4), 256, 0, stream>>>(xb, w1t, b1l, b1r, 256, xlr1, NNODES, 512, 512);
  k_fused<1, 0, 512><<<gridFused, 256, 0, stream>>>(rowstart, csrsrc, xlr1, att1, bias1, hbuf);

  // Layer 2: combined [W2l|W2r], K=256, N=1024
  k_gemm<<<dim3(gridM, 8), 256, 0, stream>>>(hbuf, w2t, b2l, b2r, 512, xlr2, NNODES, 256, 1024);
  k_fused<2, 1, 1024><<<gridFused, 256, 0, stream>>>(rowstart, csrsrc, xlr2, att2, bias2, out);
}

// Round 12
// 463.714 us; speedup vs baseline: 1.0094x; 1.0094x over previous
//
#include <hip/hip_runtime.h>

#define NNODES 50000
#define NEDGES 800000
#define ET (NEDGES + NNODES)   // 850000 edges incl. self loops
#define HEADS 4

typedef __attribute__((ext_vector_type(8))) short bf16x8;
typedef __attribute__((ext_vector_type(4))) float f32x4;
typedef __attribute__((ext_vector_type(2))) float f32x2v;

#define EXP2F(x) __builtin_amdgcn_exp2f(x)   // v_exp_f32; __exp2f collides with glibc

#if defined(__has_builtin)
#if __has_builtin(__builtin_elementwise_fma)
#define VFMA(a, b, c) __builtin_elementwise_fma((a), (b), (c))
#endif
#endif
#ifndef VFMA
__device__ inline f32x2v vfma_(f32x2v a, f32x2v b, f32x2v c) {
  f32x2v r; r.x = fmaf(a.x, b.x, c.x); r.y = fmaf(a.y, b.y, c.y); return r;
}
#define VFMA vfma_
#endif

// async global->LDS, 16B per lane (m97 recipe). Dest must be lane-linear.
#define GLOAD16(g, l) __builtin_amdgcn_global_load_lds(                      \
    (const __attribute__((address_space(1))) unsigned int*)(g),              \
    (__attribute__((address_space(3))) unsigned int*)(l), 16, 0, 0)

__device__ inline unsigned short f2bf(float f) {
  union { float f; unsigned int i; } c; c.f = f;
  unsigned int b = c.i + 0x7fffu + ((c.i >> 16) & 1u);   // RTN-even
  return (unsigned short)(b >> 16);
}
// one u32 = 2 packed bf16 -> 2 f32
__device__ inline f32x2v cvtpair(unsigned u) {
  union { unsigned i; float f; } lo, hi;
  lo.i = u << 16; hi.i = u & 0xffff0000u;
  f32x2v r; r.x = lo.f; r.y = hi.f; return r;
}
__device__ inline f32x2v vabs2(f32x2v s) {
  union { f32x2v f; unsigned u[2]; } c; c.f = s;
  c.u[0] &= 0x7fffffffu; c.u[1] &= 0x7fffffffu; return c.f;
}

// ---------------- CSR build (by dst) ----------------

__global__ void k_hist(const int* __restrict__ ei, int* __restrict__ deg) {
  int i = blockIdx.x * blockDim.x + threadIdx.x;
  if (i >= ET) return;
  int dst = (i < NEDGES) ? ei[NEDGES + i] : (i - NEDGES);
  atomicAdd(&deg[dst], 1);
}

__global__ void k_scan1(const int* __restrict__ deg, int* __restrict__ part,
                        int* __restrict__ bsum, int n) {
  __shared__ int s[256];
  int tid = threadIdx.x;
  int i = blockIdx.x * 256 + tid;
  int v = (i < n) ? deg[i] : 0;
  s[tid] = v;
  __syncthreads();
  for (int off = 1; off < 256; off <<= 1) {
    int t = (tid >= off) ? s[tid - off] : 0;
    __syncthreads();
    s[tid] += t;
    __syncthreads();
  }
  if (i < n) part[i] = s[tid] - v;
  if (tid == 255) bsum[blockIdx.x] = s[255];
}

__global__ void k_scan2(int* bsum, int nb) {
  __shared__ int s[256];
  int t = threadIdx.x;
  int v = (t < nb) ? bsum[t] : 0;
  s[t] = v;
  __syncthreads();
  for (int off = 1; off < 256; off <<= 1) {
    int tv = (t >= off) ? s[t - off] : 0;
    __syncthreads();
    s[t] += tv;
    __syncthreads();
  }
  if (t < nb) bsum[t] = s[t] - v;
}

__global__ void k_scan3(const int* __restrict__ part, const int* __restrict__ bsum,
                        int* __restrict__ rowstart, int* __restrict__ cursor,
                        int n, int total) {
  int i = blockIdx.x * blockDim.x + threadIdx.x;
  if (i < n) {
    int v = part[i] + bsum[i >> 8];
    rowstart[i] = v;
    cursor[i] = v;
  }
  if (i == n) rowstart[n] = total;
}

__global__ void k_scatter(const int* __restrict__ ei, int* __restrict__ cursor,
                          int* __restrict__ csrsrc) {
  int i = blockIdx.x * blockDim.x + threadIdx.x;
  if (i >= ET) return;
  int src, dst;
  if (i < NEDGES) { src = ei[i]; dst = ei[NEDGES + i]; }
  else            { src = dst = i - NEDGES; }
  int pos = atomicAdd(&cursor[dst], 1);
  csrsrc[pos] = src;
}

// ---------------- casts ----------------

__global__ void k_cast_bf16(const float* __restrict__ in, unsigned short* __restrict__ out, int n4) {
  int i = blockIdx.x * blockDim.x + threadIdx.x;
  if (i >= n4) return;
  float4 v = ((const float4*)in)[i];
  ushort4 o;
  o.x = f2bf(v.x); o.y = f2bf(v.y); o.z = f2bf(v.z); o.w = f2bf(v.w);
  ((ushort4*)out)[i] = o;
}

// transpose-cast via 32x32 LDS tiles: W[K][N] f32 -> T[(n+noff)][K] bf16.
__global__ __launch_bounds__(256) void k_castw_all(
    const float* __restrict__ W1l, const float* __restrict__ W1r,
    const float* __restrict__ W2l, const float* __restrict__ W2r,
    unsigned short* __restrict__ w1t, unsigned short* __restrict__ w2t) {
  __shared__ float tile[32][33];
  int which = blockIdx.y;
  const float* W;
  unsigned short* T;
  int K, N, noff;
  if (which == 0)      { W = W1l; T = w1t; K = 512; N = 256; noff = 0; }
  else if (which == 1) { W = W1r; T = w1t; K = 512; N = 256; noff = 256; }
  else if (which == 2) { W = W2l; T = w2t; K = 256; N = 512; noff = 0; }
  else                 { W = W2r; T = w2t; K = 256; N = 512; noff = 512; }
  int tpr = N >> 5;
  int tk = (blockIdx.x / tpr) << 5;
  int tn = (blockIdx.x % tpr) << 5;
  int c = threadIdx.x & 31, r = threadIdx.x >> 5;
#pragma unroll
  for (int rr = 0; rr < 32; rr += 8)
    tile[r + rr][c] = W[(size_t)(tk + r + rr) * N + tn + c];
  __syncthreads();
#pragma unroll
  for (int rr = 0; rr < 32; rr += 8)
    T[(size_t)(tn + r + rr + noff) * K + tk + c] = f2bf(tile[c][r + rr]);
}

// ---------------- bf16 MFMA GEMM, 3-buffer counted-vmcnt pipeline (T4) ----------
// C = A(M,K) * Bt(N,K)^T + bias. 128x128 tile, BK=32, linear LDS, GLOAD16 staging.
// Steady state: 3 tiles in flight, wait vmcnt(8) (= oldest tile landed), never 0.

template <int N> __device__ __forceinline__ void waitvm() {
  if constexpr (N == 0) asm volatile("s_waitcnt vmcnt(0)" ::: "memory");
  else if constexpr (N == 4) asm volatile("s_waitcnt vmcnt(4)" ::: "memory");
  else asm volatile("s_waitcnt vmcnt(8)" ::: "memory");
}

__global__ __launch_bounds__(256) void k_gemm(
    const unsigned short* __restrict__ A, const unsigned short* __restrict__ Bt,
    const float* __restrict__ bL, const float* __restrict__ bR, int nsplit,
    unsigned short* __restrict__ C, int M, int K, int N) {
  __shared__ unsigned short As[3][128 * 32];   // 3 x 8 KB
  __shared__ unsigned short Bs[3][128 * 32];
  int tid = threadIdx.x;
  int lane = tid & 63, wave = tid >> 6;
  int wr = (wave >> 1) * 64, wc = (wave & 1) * 64;
  int row0 = blockIdx.x * 128, col0 = blockIdx.y * 128;
  int fr = lane & 15, fq = lane >> 4;
  int sr = tid >> 2, sc = (tid & 3) * 8;

  const unsigned short* ga0 = &A[(size_t)(row0 + sr) * K + sc];
  const unsigned short* ga1 = &A[(size_t)(row0 + sr + 64) * K + sc];
  const unsigned short* gb0 = &Bt[(size_t)(col0 + sr) * K + sc];
  const unsigned short* gb1 = &Bt[(size_t)(col0 + sr + 64) * K + sc];

  f32x4 acc[4][4] = {};
  const int NT = K >> 5;   // 16 or 8

#define STAGE(b, k0)                                  \
  do {                                                \
    GLOAD16(ga0 + (k0), &As[b][tid * 8]);             \
    GLOAD16(ga1 + (k0), &As[b][2048 + tid * 8]);      \
    GLOAD16(gb0 + (k0), &Bs[b][tid * 8]);             \
    GLOAD16(gb1 + (k0), &Bs[b][2048 + tid * 8]);      \
  } while (0)

#define COMPUTE(b)                                                        \
  do {                                                                    \
    bf16x8 af[4], bfr[4];                                                 \
    _Pragma("unroll")                                                     \
    for (int m = 0; m < 4; ++m)                                           \
      af[m] = *(const bf16x8*)&As[b][(wr + m * 16 + fr) * 32 + fq * 8];   \
    _Pragma("unroll")                                                     \
    for (int n = 0; n < 4; ++n)                                           \
      bfr[n] = *(const bf16x8*)&Bs[b][(wc + n * 16 + fr) * 32 + fq * 8];  \
    _Pragma("unroll")                                                     \
    for (int m = 0; m < 4; ++m)                                           \
      _Pragma("unroll")                                                   \
      for (int n = 0; n < 4; ++n)                                         \
        acc[m][n] = __builtin_amdgcn_mfma_f32_16x16x32_bf16(af[m], bfr[n], acc[m][n], 0, 0, 0); \
  } while (0)

  // prologue: 3 tiles in flight
  STAGE(0, 0);
  STAGE(1, 32);
  STAGE(2, 64);

  for (int t = 0; t < NT - 3; ++t) {
    int b = t % 3;
    waitvm<8>();                      // my 4 oldest (tile t) landed
    __builtin_amdgcn_s_barrier();     // everyone's tile t landed
    COMPUTE(b);
    asm volatile("s_waitcnt lgkmcnt(0)" ::: "memory");  // my ds_reads of buf b done
    __builtin_amdgcn_sched_barrier(0);
    __builtin_amdgcn_s_barrier();     // everyone done reading buf b
    STAGE(b, (t + 3) << 5);           // overwrite buf b with tile t+3
  }
  // peeled tail: waits 8 / 4 / 0
  waitvm<8>(); __builtin_amdgcn_s_barrier(); COMPUTE((NT - 3) % 3);
  waitvm<4>(); __builtin_amdgcn_s_barrier(); COMPUTE((NT - 2) % 3);
  waitvm<0>(); __builtin_amdgcn_s_barrier(); COMPUTE((NT - 1) % 3);

#undef STAGE
#undef COMPUTE

#pragma unroll
  for (int m = 0; m < 4; ++m) {
#pragma unroll
    for (int n = 0; n < 4; ++n) {
      int col = col0 + wc + n * 16 + fr;
      float bv = (col < nsplit) ? bL[col] : bR[col - nsplit];
#pragma unroll
      for (int j = 0; j < 4; ++j) {
        int row = row0 + wr + m * 16 + fq * 4 + j;
        if (row < M) C[(size_t)row * N + col] = f2bf(acc[m][n][j] + bv);
      }
    }
  }
}

// ---------------- fused score + softmax + aggregate (bf16 inputs) ----------------
// One wave per dst; 16 lanes/head; lane covers CHL=CQ*4 contiguous channels.
// exp2-domain, no max tracking. att folded: p = sum a04*(1.5*s+|s|), a04=0.4*log2e*att.
// Packed f32 (float2) math -> v_pk_add/v_pk_fma. Ping-pong 4-edge blocks: next
// block's gathers issued before current block's compute (latency overlap).

template <int CQ> struct raw_t;
template <> struct raw_t<1> { using T = uint2; };
template <> struct raw_t<2> { using T = uint4; };

template <int CQ>
__device__ __forceinline__ void rawwords(const typename raw_t<CQ>::T& r, unsigned* u) {
  u[0] = r.x; u[1] = r.y;
  if constexpr (CQ == 2) { u[2] = r.z; u[3] = r.w; }
}

template <int CQ, int MODE, int STR>
__global__ __launch_bounds__(256) void k_fused(
    const int* __restrict__ rowstart, const int* __restrict__ csrsrc,
    const unsigned short* __restrict__ xlr,
    const float* __restrict__ att, const float* __restrict__ bias,
    void* __restrict__ outp) {
  const int C = CQ * 64;
  const int CHL = CQ * 4;
  const int P = CQ * 2;              // f32 pairs per lane
  using RawT = typename raw_t<CQ>::T;
  int dst = (blockIdx.x * blockDim.x + threadIdx.x) >> 6;
  int lane = threadIdx.x & 63;
  if (dst >= NNODES) return;
  int h = lane >> 4;
  int l = lane & 15;
  const int choff = h * C + l * CHL;

  f32x2v xr2[P], a04[P];
  {
    RawT xrr = *(const RawT*)&xlr[(size_t)dst * STR + STR / 2 + choff];
    unsigned u[4];
    rawwords<CQ>(xrr, u);
#pragma unroll
    for (int j = 0; j < P; ++j) {
      xr2[j] = cvtpair(u[j]);
      a04[j].x = att[choff + j * 2 + 0] * (0.4f * 1.44269504f);
      a04[j].y = att[choff + j * 2 + 1] * (0.4f * 1.44269504f);
    }
  }
  const f32x2v c15 = {1.5f, 1.5f};

  int rs = __builtin_amdgcn_readfirstlane(rowstart[dst]);
  int re = __builtin_amdgcn_readfirstlane(rowstart[dst + 1]);

  float den = 0.f;
  f32x2v acc2[P];
#pragma unroll
  for (int j = 0; j < P; ++j) acc2[j] = (f32x2v){0.f, 0.f};

  // score from raw (converts on the fly; pk add/fma)
  auto score = [&](const RawT& r) -> float {
    unsigned u[4];
    rawwords<CQ>(r, u);
    f32x2v p2 = {0.f, 0.f};
#pragma unroll
    for (int j = 0; j < P; ++j) {
      f32x2v x2 = cvtpair(u[j]);
      f32x2v s = x2 + xr2[j];
      f32x2v inner = VFMA(c15, s, vabs2(s));   // 1.5*s + |s|
      p2 = VFMA(a04[j], inner, p2);
    }
    return p2.x + p2.y;
  };

  auto load4 = [&](RawT& r0, RawT& r1, RawT& r2, RawT& r3, int idx) {
    int s0 = csrsrc[idx + 0];
    int s1 = csrsrc[idx + 1];
    int s2 = csrsrc[idx + 2];
    int s3 = csrsrc[idx + 3];
    r0 = *(const RawT*)&xlr[(unsigned)s0 * (unsigned)STR + choff];
    r1 = *(const RawT*)&xlr[(unsigned)s1 * (unsigned)STR + choff];
    r2 = *(const RawT*)&xlr[(unsigned)s2 * (unsigned)STR + choff];
    r3 = *(const RawT*)&xlr[(unsigned)s3 * (unsigned)STR + choff];
  };

  auto consume4 = [&](const RawT& r0, const RawT& r1, const RawT& r2, const RawT& r3) {
    float p0 = score(r0);
    float p1 = score(r1);
    float p2 = score(r2);
    float p3 = score(r3);
#pragma unroll
    for (int d = 1; d <= 8; d <<= 1) {
      p0 += __shfl_xor(p0, d);
      p1 += __shfl_xor(p1, d);
      p2 += __shfl_xor(p2, d);
      p3 += __shfl_xor(p3, d);
    }
    float w0 = EXP2F(p0), w1 = EXP2F(p1), w2 = EXP2F(p2), w3 = EXP2F(p3);
    den += (w0 + w1) + (w2 + w3);
    f32x2v w0v = {w0, w0}, w1v = {w1, w1}, w2v = {w2, w2}, w3v = {w3, w3};
    unsigned u0[4], u1[4], u2[4], u3[4];
    rawwords<CQ>(r0, u0); rawwords<CQ>(r1, u1);
    rawwords<CQ>(r2, u2); rawwords<CQ>(r3, u3);
#pragma unroll
    for (int j = 0; j < P; ++j) {
      f32x2v a = acc2[j];
      a = VFMA(w0v, cvtpair(u0[j]), a);
      a = VFMA(w1v, cvtpair(u1[j]), a);
      a = VFMA(w2v, cvtpair(u2[j]), a);
      a = VFMA(w3v, cvtpair(u3[j]), a);
      acc2[j] = a;
    }
  };

  int nb = (re - rs) >> 2;   // full 4-edge blocks
  int i = rs;
  if (nb > 0) {
    RawT A0, A1, A2, A3, B0, B1, B2, B3;
    load4(A0, A1, A2, A3, i);
    for (int b = 1; b < nb; ++b) {
      if (b & 1) { load4(B0, B1, B2, B3, i + 4); consume4(A0, A1, A2, A3); }
      else       { load4(A0, A1, A2, A3, i + 4); consume4(B0, B1, B2, B3); }
      i += 4;
    }
    if (nb & 1) consume4(A0, A1, A2, A3);
    else        consume4(B0, B1, B2, B3);
    i += 4;
  }
  for (; i < re; ++i) {   // scalar tail (<=3 edges)
    int s0 = csrsrc[i];
    RawT r0 = *(const RawT*)&xlr[(unsigned)s0 * (unsigned)STR + choff];
    float p0 = score(r0);
#pragma unroll
    for (int d = 1; d <= 8; d <<= 1) p0 += __shfl_xor(p0, d);
    float w0 = EXP2F(p0);
    den += w0;
    f32x2v wv = {w0, w0};
    unsigned u[4];
    rawwords<CQ>(r0, u);
#pragma unroll
    for (int j = 0; j < P; ++j) acc2[j] = VFMA(wv, cvtpair(u[j]), acc2[j]);
  }

  float inv = 1.f / (den + 1e-16f);

  if (MODE == 0) {
    unsigned short* out = (unsigned short*)outp;
#pragma unroll
    for (int q = 0; q < CQ; ++q) {
      const float4 bv = *(const float4*)&bias[choff + q * 4];
      ushort4 o;
      o.x = f2bf(fmaxf(acc2[q * 2 + 0].x * inv + bv.x, 0.f));
      o.y = f2bf(fmaxf(acc2[q * 2 + 0].y * inv + bv.y, 0.f));
      o.z = f2bf(fmaxf(acc2[q * 2 + 1].x * inv + bv.z, 0.f));
      o.w = f2bf(fmaxf(acc2[q * 2 + 1].y * inv + bv.w, 0.f));
      *(ushort4*)&out[(size_t)dst * (HEADS * C) + choff + q * 4] = o;
    }
  } else {
    float* out = (float*)outp;
    float rr[8];   // CHL <= 8
#pragma unroll
    for (int j = 0; j < P; ++j) {
      rr[j * 2 + 0] = acc2[j].x * inv;
      rr[j * 2 + 1] = acc2[j].y * inv;
    }
#pragma unroll
    for (int c = 0; c < CHL; ++c) {
      rr[c] += __shfl_xor(rr[c], 16);   // sum across heads
      rr[c] += __shfl_xor(rr[c], 32);
    }
    if (lane < 16) {
#pragma unroll
      for (int q = 0; q < CQ; ++q) {
        int c = lane * CHL + q * 4;
        float4 o;
        o.x = rr[q * 4 + 0] * 0.25f + bias[c + 0];
        o.y = rr[q * 4 + 1] * 0.25f + bias[c + 1];
        o.z = rr[q * 4 + 2] * 0.25f + bias[c + 2];
        o.w = rr[q * 4 + 3] * 0.25f + bias[c + 3];
        *(float4*)&out[(size_t)dst * C + c] = o;
      }
    }
  }
}

// ---------------- orchestration ----------------

extern "C" void kernel_launch(void* const* d_in, const int* in_sizes, int n_in,
                              void* d_out, int out_size, void* d_ws, size_t ws_size,
                              hipStream_t stream) {
  (void)in_sizes; (void)n_in; (void)out_size; (void)ws_size;
  const float* x     = (const float*)d_in[0];
  const int*   ei    = (const int*)d_in[1];
  const float* W1l   = (const float*)d_in[2];
  const float* b1l   = (const float*)d_in[3];
  const float* W1r   = (const float*)d_in[4];
  const float* b1r   = (const float*)d_in[5];
  const float* att1  = (const float*)d_in[6];
  const float* bias1 = (const float*)d_in[7];
  const float* W2l   = (const float*)d_in[8];
  const float* b2l   = (const float*)d_in[9];
  const float* W2r   = (const float*)d_in[10];
  const float* b2r   = (const float*)d_in[11];
  const float* att2  = (const float*)d_in[12];
  const float* bias2 = (const float*)d_in[13];
  float* out = (float*)d_out;

  char* ws = (char*)d_ws;
  size_t off = 0;
  auto alloc = [&](size_t bytes) {
    char* p = ws + off;
    off = (off + bytes + 255) & ~(size_t)255;
    return p;
  };
  int*  deg      = (int*)alloc((size_t)NNODES * 4);
  int*  part     = (int*)alloc((size_t)NNODES * 4);
  int*  bsum     = (int*)alloc(256 * 4);
  int*  rowstart = (int*)alloc((size_t)(NNODES + 1) * 4);
  int*  cursor   = (int*)alloc((size_t)NNODES * 4);
  int*  csrsrc   = (int*)alloc((size_t)ET * 4);
  unsigned short* xb   = (unsigned short*)alloc((size_t)NNODES * 512 * 2);
  unsigned short* w1t  = (unsigned short*)alloc((size_t)512 * 512 * 2);
  unsigned short* w2t  = (unsigned short*)alloc((size_t)1024 * 256 * 2);
  unsigned short* xlr1 = (unsigned short*)alloc((size_t)NNODES * 512 * 2);
  unsigned short* hbuf = (unsigned short*)alloc((size_t)NNODES * 256 * 2);
  unsigned short* xlr2 = (unsigned short*)alloc((size_t)NNODES * 1024 * 2);
  (void)alloc(64 * 1024);   // tail pad for GEMM A-row overrun reads

  // CSR build
  (void)hipMemsetAsync(deg, 0, (size_t)NNODES * 4, stream);
  k_hist<<<(ET + 255) / 256, 256, 0, stream>>>(ei, deg);
  int nb = (NNODES + 255) / 256;
  k_scan1<<<nb, 256, 0, stream>>>(deg, part, bsum, NNODES);
  k_scan2<<<1, 256, 0, stream>>>(bsum, nb);
  k_scan3<<<(NNODES + 256) / 256, 256, 0, stream>>>(part, bsum, rowstart, cursor, NNODES, ET);
  k_scatter<<<(ET + 255) / 256, 256, 0, stream>>>(ei, cursor, csrsrc);

  // casts
  k_cast_bf16<<<(NNODES * 512 / 4 + 255) / 256, 256, 0, stream>>>(x, xb, NNODES * 512 / 4);
  k_castw_all<<<dim3(128, 4), 256, 0, stream>>>(W1l, W1r, W2l, W2r, w1t, w2t);

  const int gridM = (NNODES + 127) / 128;   // 391
  const int gridFused = (NNODES + 3) / 4;   // 4 waves/block

  // Layer 1: combined [W1l|W1r], K=512, N=512
  k_gemm<<<dim3(gridM, 4), 256, 0, stream>>>(xb, w1t, b1l, b1r, 256, xlr1, NNODES, 512, 512);
  k_fused<1, 0, 512><<<gridFused, 256, 0, stream>>>(rowstart, csrsrc, xlr1, att1, bias1, hbuf);

  // Layer 2: combined [W2l|W2r], K=256, N=1024
  k_gemm<<<dim3(gridM, 8), 256, 0, stream>>>(hbuf, w2t, b2l, b2r, 512, xlr2, NNODES, 256, 1024);
  k_fused<2, 1, 1024><<<gridFused, 256, 0, stream>>>(rowstart, csrsrc, xlr2, att2, bias2, out);
}

// Round 13
// 453.592 us; speedup vs baseline: 1.0319x; 1.0223x over previous
//
#include <hip/hip_runtime.h>

#define NNODES 50000
#define NEDGES 800000
#define ET (NEDGES + NNODES)   // 850000 edges incl. self loops
#define HEADS 4

typedef __attribute__((ext_vector_type(8))) short bf16x8;
typedef __attribute__((ext_vector_type(4))) float f32x4;

#define EXP2F(x) __builtin_amdgcn_exp2f(x)   // v_exp_f32; __exp2f collides with glibc

// async global->LDS, 16B per lane (m97 recipe). Dest must be lane-linear.
#define GLOAD16(g, l) __builtin_amdgcn_global_load_lds(                      \
    (const __attribute__((address_space(1))) unsigned int*)(g),              \
    (__attribute__((address_space(3))) unsigned int*)(l), 16, 0, 0)

__device__ inline unsigned short f2bf(float f) {
  union { float f; unsigned int i; } c; c.f = f;
  unsigned int b = c.i + 0x7fffu + ((c.i >> 16) & 1u);   // RTN-even
  return (unsigned short)(b >> 16);
}
__device__ inline float4 b4tof(uint2 r) {
  float4 f;
  union { unsigned int i; float v; } c;
  c.i = r.x << 16;          f.x = c.v;
  c.i = r.x & 0xffff0000u;  f.y = c.v;
  c.i = r.y << 16;          f.z = c.v;
  c.i = r.y & 0xffff0000u;  f.w = c.v;
  return f;
}

// ---------------- CSR build (by dst) ----------------

__global__ void k_hist(const int* __restrict__ ei, int* __restrict__ deg) {
  int i = blockIdx.x * blockDim.x + threadIdx.x;
  if (i >= ET) return;
  int dst = (i < NEDGES) ? ei[NEDGES + i] : (i - NEDGES);
  atomicAdd(&deg[dst], 1);
}

__global__ void k_scan1(const int* __restrict__ deg, int* __restrict__ part,
                        int* __restrict__ bsum, int n) {
  __shared__ int s[256];
  int tid = threadIdx.x;
  int i = blockIdx.x * 256 + tid;
  int v = (i < n) ? deg[i] : 0;
  s[tid] = v;
  __syncthreads();
  for (int off = 1; off < 256; off <<= 1) {
    int t = (tid >= off) ? s[tid - off] : 0;
    __syncthreads();
    s[tid] += t;
    __syncthreads();
  }
  if (i < n) part[i] = s[tid] - v;
  if (tid == 255) bsum[blockIdx.x] = s[255];
}

__global__ void k_scan2(int* bsum, int nb) {
  __shared__ int s[256];
  int t = threadIdx.x;
  int v = (t < nb) ? bsum[t] : 0;
  s[t] = v;
  __syncthreads();
  for (int off = 1; off < 256; off <<= 1) {
    int tv = (t >= off) ? s[t - off] : 0;
    __syncthreads();
    s[t] += tv;
    __syncthreads();
  }
  if (t < nb) bsum[t] = s[t] - v;
}

__global__ void k_scan3(const int* __restrict__ part, const int* __restrict__ bsum,
                        int* __restrict__ rowstart, int* __restrict__ cursor,
                        int n, int total) {
  int i = blockIdx.x * blockDim.x + threadIdx.x;
  if (i < n) {
    int v = part[i] + bsum[i >> 8];
    rowstart[i] = v;
    cursor[i] = v;
  }
  if (i == n) rowstart[n] = total;
}

__global__ void k_scatter(const int* __restrict__ ei, int* __restrict__ cursor,
                          int* __restrict__ csrsrc) {
  int i = blockIdx.x * blockDim.x + threadIdx.x;
  if (i >= ET) return;
  int src, dst;
  if (i < NEDGES) { src = ei[i]; dst = ei[NEDGES + i]; }
  else            { src = dst = i - NEDGES; }
  int pos = atomicAdd(&cursor[dst], 1);
  csrsrc[pos] = src;
}

// ---------------- casts ----------------

__global__ void k_cast_bf16(const float* __restrict__ in, unsigned short* __restrict__ out, int n4) {
  int i = blockIdx.x * blockDim.x + threadIdx.x;
  if (i >= n4) return;
  float4 v = ((const float4*)in)[i];
  ushort4 o;
  o.x = f2bf(v.x); o.y = f2bf(v.y); o.z = f2bf(v.z); o.w = f2bf(v.w);
  ((ushort4*)out)[i] = o;
}

// transpose-cast via 32x32 LDS tiles: W[K][N] f32 -> T[(n+noff)][K] bf16.
__global__ __launch_bounds__(256) void k_castw_all(
    const float* __restrict__ W1l, const float* __restrict__ W1r,
    const float* __restrict__ W2l, const float* __restrict__ W2r,
    unsigned short* __restrict__ w1t, unsigned short* __restrict__ w2t) {
  __shared__ float tile[32][33];
  int which = blockIdx.y;
  const float* W;
  unsigned short* T;
  int K, N, noff;
  if (which == 0)      { W = W1l; T = w1t; K = 512; N = 256; noff = 0; }
  else if (which == 1) { W = W1r; T = w1t; K = 512; N = 256; noff = 256; }
  else if (which == 2) { W = W2l; T = w2t; K = 256; N = 512; noff = 0; }
  else                 { W = W2r; T = w2t; K = 256; N = 512; noff = 512; }
  int tpr = N >> 5;
  int tk = (blockIdx.x / tpr) << 5;
  int tn = (blockIdx.x % tpr) << 5;
  int c = threadIdx.x & 31, r = threadIdx.x >> 5;
#pragma unroll
  for (int rr = 0; rr < 32; rr += 8)
    tile[r + rr][c] = W[(size_t)(tk + r + rr) * N + tn + c];
  __syncthreads();
#pragma unroll
  for (int rr = 0; rr < 32; rr += 8)
    T[(size_t)(tn + r + rr + noff) * K + tk + c] = f2bf(tile[c][r + rr]);
}

// ---------------- bf16 MFMA GEMM, 3-buffer counted-vmcnt pipeline (T4) ----------
// C = A(M,K) * Bt(N,K)^T + bias. 128x128 tile, BK=32, linear LDS, GLOAD16 staging.
// Steady state: 3 tiles in flight, wait vmcnt(8) (= oldest tile landed), never 0.

template <int N> __device__ __forceinline__ void waitvm() {
  if constexpr (N == 0) asm volatile("s_waitcnt vmcnt(0)" ::: "memory");
  else if constexpr (N == 4) asm volatile("s_waitcnt vmcnt(4)" ::: "memory");
  else asm volatile("s_waitcnt vmcnt(8)" ::: "memory");
}

__global__ __launch_bounds__(256) void k_gemm(
    const unsigned short* __restrict__ A, const unsigned short* __restrict__ Bt,
    const float* __restrict__ bL, const float* __restrict__ bR, int nsplit,
    unsigned short* __restrict__ C, int M, int K, int N) {
  __shared__ unsigned short As[3][128 * 32];   // 3 x 8 KB
  __shared__ unsigned short Bs[3][128 * 32];
  int tid = threadIdx.x;
  int lane = tid & 63, wave = tid >> 6;
  int wr = (wave >> 1) * 64, wc = (wave & 1) * 64;
  int row0 = blockIdx.x * 128, col0 = blockIdx.y * 128;
  int fr = lane & 15, fq = lane >> 4;
  int sr = tid >> 2, sc = (tid & 3) * 8;

  const unsigned short* ga0 = &A[(size_t)(row0 + sr) * K + sc];
  const unsigned short* ga1 = &A[(size_t)(row0 + sr + 64) * K + sc];
  const unsigned short* gb0 = &Bt[(size_t)(col0 + sr) * K + sc];
  const unsigned short* gb1 = &Bt[(size_t)(col0 + sr + 64) * K + sc];

  f32x4 acc[4][4] = {};
  const int NT = K >> 5;   // 16 or 8

#define STAGE(b, k0)                                  \
  do {                                                \
    GLOAD16(ga0 + (k0), &As[b][tid * 8]);             \
    GLOAD16(ga1 + (k0), &As[b][2048 + tid * 8]);      \
    GLOAD16(gb0 + (k0), &Bs[b][tid * 8]);             \
    GLOAD16(gb1 + (k0), &Bs[b][2048 + tid * 8]);      \
  } while (0)

#define COMPUTE(b)                                                        \
  do {                                                                    \
    bf16x8 af[4], bfr[4];                                                 \
    _Pragma("unroll")                                                     \
    for (int m = 0; m < 4; ++m)                                           \
      af[m] = *(const bf16x8*)&As[b][(wr + m * 16 + fr) * 32 + fq * 8];   \
    _Pragma("unroll")                                                     \
    for (int n = 0; n < 4; ++n)                                           \
      bfr[n] = *(const bf16x8*)&Bs[b][(wc + n * 16 + fr) * 32 + fq * 8];  \
    _Pragma("unroll")                                                     \
    for (int m = 0; m < 4; ++m)                                           \
      _Pragma("unroll")                                                   \
      for (int n = 0; n < 4; ++n)                                         \
        acc[m][n] = __builtin_amdgcn_mfma_f32_16x16x32_bf16(af[m], bfr[n], acc[m][n], 0, 0, 0); \
  } while (0)

  // prologue: 3 tiles in flight
  STAGE(0, 0);
  STAGE(1, 32);
  STAGE(2, 64);

  for (int t = 0; t < NT - 3; ++t) {
    int b = t % 3;
    waitvm<8>();                      // my 4 oldest (tile t) landed
    __builtin_amdgcn_s_barrier();     // everyone's tile t landed
    COMPUTE(b);
    asm volatile("s_waitcnt lgkmcnt(0)" ::: "memory");  // my ds_reads of buf b done
    __builtin_amdgcn_sched_barrier(0);
    __builtin_amdgcn_s_barrier();     // everyone done reading buf b
    STAGE(b, (t + 3) << 5);           // overwrite buf b with tile t+3
  }
  // peeled tail: waits 8 / 4 / 0
  waitvm<8>(); __builtin_amdgcn_s_barrier(); COMPUTE((NT - 3) % 3);
  waitvm<4>(); __builtin_amdgcn_s_barrier(); COMPUTE((NT - 2) % 3);
  waitvm<0>(); __builtin_amdgcn_s_barrier(); COMPUTE((NT - 1) % 3);

#undef STAGE
#undef COMPUTE

#pragma unroll
  for (int m = 0; m < 4; ++m) {
#pragma unroll
    for (int n = 0; n < 4; ++n) {
      int col = col0 + wc + n * 16 + fr;
      float bv = (col < nsplit) ? bL[col] : bR[col - nsplit];
#pragma unroll
      for (int j = 0; j < 4; ++j) {
        int row = row0 + wr + m * 16 + fq * 4 + j;
        if (row < M) C[(size_t)row * N + col] = f2bf(acc[m][n][j] + bv);
      }
    }
  }
}

// ---------------- fused score + softmax + aggregate (bf16 inputs) ----------------
// One wave per dst; 16 lanes per head; lane covers CHL=CQ*4 CONTIGUOUS channels
// (CQ=1: uint2 8B gather, CQ=2: uint4 16B gather - single load per edge).
// exp2-domain, no max tracking (|p|<~15 by construction). 4-edge unroll.
// Score: att*lrelu(s) == a04*(1.5*s+|s|), a04 = 0.4*log2e*att (|s| is a free
// input modifier) -> 3 VALU/channel instead of 4.

template <int CQ>
__device__ inline void load_row(const unsigned short* p, float4* xv) {
  if constexpr (CQ == 1) {
    xv[0] = b4tof(*(const uint2*)p);
  } else {
    uint4 r = *(const uint4*)p;
    xv[0] = b4tof(make_uint2(r.x, r.y));
    xv[1] = b4tof(make_uint2(r.z, r.w));
  }
}

template <int CQ>
__device__ inline float edge_score(const float4* xv, const float4* xrv, const float4* a04) {
  float p = 0.f;
#pragma unroll
  for (int q = 0; q < CQ; ++q) {
    float s;
    s = xv[q].x + xrv[q].x; p = fmaf(a04[q].x, fmaf(1.5f, s, fabsf(s)), p);
    s = xv[q].y + xrv[q].y; p = fmaf(a04[q].y, fmaf(1.5f, s, fabsf(s)), p);
    s = xv[q].z + xrv[q].z; p = fmaf(a04[q].z, fmaf(1.5f, s, fabsf(s)), p);
    s = xv[q].w + xrv[q].w; p = fmaf(a04[q].w, fmaf(1.5f, s, fabsf(s)), p);
  }
  return p;
}

template <int CQ, int MODE, int STR>
__global__ __launch_bounds__(256) void k_fused(
    const int* __restrict__ rowstart, const int* __restrict__ csrsrc,
    const unsigned short* __restrict__ xlr,
    const float* __restrict__ att, const float* __restrict__ bias,
    void* __restrict__ outp) {
  const int C = CQ * 64;
  const int CHL = CQ * 4;            // contiguous channels per lane
  int dst = (blockIdx.x * blockDim.x + threadIdx.x) >> 6;
  int lane = threadIdx.x & 63;
  if (dst >= NNODES) return;
  int h = lane >> 4;
  int l = lane & 15;
  const int choff = h * C + l * CHL;

  float4 xrv[CQ], a04[CQ];
  load_row<CQ>(&xlr[(size_t)dst * STR + STR / 2 + choff], xrv);
#pragma unroll
  for (int q = 0; q < CQ; ++q) {
    float4 a = *(const float4*)&att[choff + q * 4];
    const float k = 0.4f * 1.44269504f;   // 0.4 * log2(e)
    a.x *= k; a.y *= k; a.z *= k; a.w *= k;
    a04[q] = a;
  }

  int rs = __builtin_amdgcn_readfirstlane(rowstart[dst]);
  int re = __builtin_amdgcn_readfirstlane(rowstart[dst + 1]);

  float den = 0.f;
  float4 acc[CQ];
#pragma unroll
  for (int q = 0; q < CQ; ++q) acc[q] = make_float4(0.f, 0.f, 0.f, 0.f);

  int i = rs;
  for (; i + 4 <= re; i += 4) {
    int s0 = csrsrc[i + 0];
    int s1 = csrsrc[i + 1];
    int s2 = csrsrc[i + 2];
    int s3 = csrsrc[i + 3];
    float4 x0[CQ], x1[CQ], x2[CQ], x3[CQ];
    load_row<CQ>(&xlr[(unsigned)s0 * (unsigned)STR + choff], x0);
    load_row<CQ>(&xlr[(unsigned)s1 * (unsigned)STR + choff], x1);
    load_row<CQ>(&xlr[(unsigned)s2 * (unsigned)STR + choff], x2);
    load_row<CQ>(&xlr[(unsigned)s3 * (unsigned)STR + choff], x3);
    float p0 = edge_score<CQ>(x0, xrv, a04);
    float p1 = edge_score<CQ>(x1, xrv, a04);
    float p2 = edge_score<CQ>(x2, xrv, a04);
    float p3 = edge_score<CQ>(x3, xrv, a04);
#pragma unroll
    for (int d = 1; d <= 8; d <<= 1) {
      p0 += __shfl_xor(p0, d);
      p1 += __shfl_xor(p1, d);
      p2 += __shfl_xor(p2, d);
      p3 += __shfl_xor(p3, d);
    }
    float w0 = EXP2F(p0), w1 = EXP2F(p1), w2 = EXP2F(p2), w3 = EXP2F(p3);
    den += (w0 + w1) + (w2 + w3);
#pragma unroll
    for (int q = 0; q < CQ; ++q) {
      acc[q].x = fmaf(w0, x0[q].x, fmaf(w1, x1[q].x, fmaf(w2, x2[q].x, fmaf(w3, x3[q].x, acc[q].x))));
      acc[q].y = fmaf(w0, x0[q].y, fmaf(w1, x1[q].y, fmaf(w2, x2[q].y, fmaf(w3, x3[q].y, acc[q].y))));
      acc[q].z = fmaf(w0, x0[q].z, fmaf(w1, x1[q].z, fmaf(w2, x2[q].z, fmaf(w3, x3[q].z, acc[q].z))));
      acc[q].w = fmaf(w0, x0[q].w, fmaf(w1, x1[q].w, fmaf(w2, x2[q].w, fmaf(w3, x3[q].w, acc[q].w))));
    }
  }
  for (; i < re; ++i) {
    int s0 = csrsrc[i];
    float4 x0[CQ];
    load_row<CQ>(&xlr[(unsigned)s0 * (unsigned)STR + choff], x0);
    float p0 = edge_score<CQ>(x0, xrv, a04);
#pragma unroll
    for (int d = 1; d <= 8; d <<= 1) p0 += __shfl_xor(p0, d);
    float w0 = EXP2F(p0);
    den += w0;
#pragma unroll
    for (int q = 0; q < CQ; ++q) {
      acc[q].x = fmaf(w0, x0[q].x, acc[q].x);
      acc[q].y = fmaf(w0, x0[q].y, acc[q].y);
      acc[q].z = fmaf(w0, x0[q].z, acc[q].z);
      acc[q].w = fmaf(w0, x0[q].w, acc[q].w);
    }
  }

  float inv = 1.f / (den + 1e-16f);

  if (MODE == 0) {
    unsigned short* out = (unsigned short*)outp;
#pragma unroll
    for (int q = 0; q < CQ; ++q) {
      const float4 bv = *(const float4*)&bias[choff + q * 4];
      ushort4 o;
      o.x = f2bf(fmaxf(acc[q].x * inv + bv.x, 0.f));
      o.y = f2bf(fmaxf(acc[q].y * inv + bv.y, 0.f));
      o.z = f2bf(fmaxf(acc[q].z * inv + bv.z, 0.f));
      o.w = f2bf(fmaxf(acc[q].w * inv + bv.w, 0.f));
      *(ushort4*)&out[(size_t)dst * (HEADS * C) + choff + q * 4] = o;
    }
  } else {
    float* out = (float*)outp;
    float r[CQ][4];
#pragma unroll
    for (int q = 0; q < CQ; ++q) {
      r[q][0] = acc[q].x * inv; r[q][1] = acc[q].y * inv;
      r[q][2] = acc[q].z * inv; r[q][3] = acc[q].w * inv;
    }
#pragma unroll
    for (int q = 0; q < CQ; ++q)
#pragma unroll
      for (int j = 0; j < 4; ++j) {
        r[q][j] += __shfl_xor(r[q][j], 16);   // sum across heads
        r[q][j] += __shfl_xor(r[q][j], 32);
      }
    if (lane < 16) {
#pragma unroll
      for (int q = 0; q < CQ; ++q) {
        int c = lane * CHL + q * 4;
        float4 o;
        o.x = r[q][0] * 0.25f + bias[c + 0];
        o.y = r[q][1] * 0.25f + bias[c + 1];
        o.z = r[q][2] * 0.25f + bias[c + 2];
        o.w = r[q][3] * 0.25f + bias[c + 3];
        *(float4*)&out[(size_t)dst * C + c] = o;
      }
    }
  }
}

// ---------------- orchestration ----------------

extern "C" void kernel_launch(void* const* d_in, const int* in_sizes, int n_in,
                              void* d_out, int out_size, void* d_ws, size_t ws_size,
                              hipStream_t stream) {
  (void)in_sizes; (void)n_in; (void)out_size; (void)ws_size;
  const float* x     = (const float*)d_in[0];
  const int*   ei    = (const int*)d_in[1];
  const float* W1l   = (const float*)d_in[2];
  const float* b1l   = (const float*)d_in[3];
  const float* W1r   = (const float*)d_in[4];
  const float* b1r   = (const float*)d_in[5];
  const float* att1  = (const float*)d_in[6];
  const float* bias1 = (const float*)d_in[7];
  const float* W2l   = (const float*)d_in[8];
  const float* b2l   = (const float*)d_in[9];
  const float* W2r   = (const float*)d_in[10];
  const float* b2r   = (const float*)d_in[11];
  const float* att2  = (const float*)d_in[12];
  const float* bias2 = (const float*)d_in[13];
  float* out = (float*)d_out;

  char* ws = (char*)d_ws;
  size_t off = 0;
  auto alloc = [&](size_t bytes) {
    char* p = ws + off;
    off = (off + bytes + 255) & ~(size_t)255;
    return p;
  };
  int*  deg      = (int*)alloc((size_t)NNODES * 4);
  int*  part     = (int*)alloc((size_t)NNODES * 4);
  int*  bsum     = (int*)alloc(256 * 4);
  int*  rowstart = (int*)alloc((size_t)(NNODES + 1) * 4);
  int*  cursor   = (int*)alloc((size_t)NNODES * 4);
  int*  csrsrc   = (int*)alloc((size_t)ET * 4);
  unsigned short* xb   = (unsigned short*)alloc((size_t)NNODES * 512 * 2);
  unsigned short* w1t  = (unsigned short*)alloc((size_t)512 * 512 * 2);
  unsigned short* w2t  = (unsigned short*)alloc((size_t)1024 * 256 * 2);
  unsigned short* xlr1 = (unsigned short*)alloc((size_t)NNODES * 512 * 2);
  unsigned short* hbuf = (unsigned short*)alloc((size_t)NNODES * 256 * 2);
  unsigned short* xlr2 = (unsigned short*)alloc((size_t)NNODES * 1024 * 2);
  (void)alloc(64 * 1024);   // tail pad for GEMM A-row overrun reads

  // CSR build
  (void)hipMemsetAsync(deg, 0, (size_t)NNODES * 4, stream);
  k_hist<<<(ET + 255) / 256, 256, 0, stream>>>(ei, deg);
  int nb = (NNODES + 255) / 256;
  k_scan1<<<nb, 256, 0, stream>>>(deg, part, bsum, NNODES);
  k_scan2<<<1, 256, 0, stream>>>(bsum, nb);
  k_scan3<<<(NNODES + 256) / 256, 256, 0, stream>>>(part, bsum, rowstart, cursor, NNODES, ET);
  k_scatter<<<(ET + 255) / 256, 256, 0, stream>>>(ei, cursor, csrsrc);

  // casts
  k_cast_bf16<<<(NNODES * 512 / 4 + 255) / 256, 256, 0, stream>>>(x, xb, NNODES * 512 / 4);
  k_castw_all<<<dim3(128, 4), 256, 0, stream>>>(W1l, W1r, W2l, W2r, w1t, w2t);

  const int gridM = (NNODES + 127) / 128;   // 391
  const int gridFused = (NNODES + 3) / 4;   // 4 waves/block

  // Layer 1: combined [W1l|W1r], K=512, N=512
  k_gemm<<<dim3(gridM, 4), 256, 0, stream>>>(xb, w1t, b1l, b1r, 256, xlr1, NNODES, 512, 512);
  k_fused<1, 0, 512><<<gridFused, 256, 0, stream>>>(rowstart, csrsrc, xlr1, att1, bias1, hbuf);

  // Layer 2: combined [W2l|W2r], K=256, N=1024
  k_gemm<<<dim3(gridM, 8), 256, 0, stream>>>(hbuf, w2t, b2l, b2r, 512, xlr2, NNODES, 256, 1024);
  k_fused<2, 1, 1024><<<gridFused, 256, 0, stream>>>(rowstart, csrsrc, xlr2, att2, bias2, out);
}

// Round 14
// 448.048 us; speedup vs baseline: 1.0447x; 1.0124x over previous
//
#include <hip/hip_runtime.h>

#define NNODES 50000
#define NEDGES 800000
#define ET (NEDGES + NNODES)   // 850000 edges incl. self loops
#define HEADS 4

typedef __attribute__((ext_vector_type(8))) short bf16x8;
typedef __attribute__((ext_vector_type(4))) float f32x4;
typedef __attribute__((ext_vector_type(2))) float f32x2v;

#define EXP2F(x) __builtin_amdgcn_exp2f(x)   // v_exp_f32; __exp2f collides with glibc

#if defined(__has_builtin)
#if __has_builtin(__builtin_elementwise_fma)
#define VFMA(a, b, c) __builtin_elementwise_fma((a), (b), (c))
#endif
#if __has_builtin(__builtin_elementwise_max)
#define VMAX(a, b) __builtin_elementwise_max((a), (b))
#endif
#endif
#ifndef VFMA
__device__ inline f32x2v vfma_(f32x2v a, f32x2v b, f32x2v c) {
  f32x2v r; r.x = fmaf(a.x, b.x, c.x); r.y = fmaf(a.y, b.y, c.y); return r;
}
#define VFMA vfma_
#endif
#ifndef VMAX
__device__ inline f32x2v vmax_(f32x2v a, f32x2v b) {
  f32x2v r; r.x = fmaxf(a.x, b.x); r.y = fmaxf(a.y, b.y); return r;
}
#define VMAX vmax_
#endif

// async global->LDS, 16B per lane (m97 recipe). Dest must be lane-linear.
#define GLOAD16(g, l) __builtin_amdgcn_global_load_lds(                      \
    (const __attribute__((address_space(1))) unsigned int*)(g),              \
    (__attribute__((address_space(3))) unsigned int*)(l), 16, 0, 0)

__device__ inline unsigned short f2bf(float f) {
  union { float f; unsigned int i; } c; c.f = f;
  unsigned int b = c.i + 0x7fffu + ((c.i >> 16) & 1u);   // RTN-even
  return (unsigned short)(b >> 16);
}
// one u32 = 2 packed bf16 -> f32 pair (1 lshl + 1 and)
__device__ inline f32x2v cvtpair(unsigned u) {
  union { unsigned i; float f; } lo, hi;
  lo.i = u << 16; hi.i = u & 0xffff0000u;
  f32x2v r; r.x = lo.f; r.y = hi.f; return r;
}

// ---------------- CSR build (by dst) ----------------

__global__ void k_hist(const int* __restrict__ ei, int* __restrict__ deg) {
  int i = blockIdx.x * blockDim.x + threadIdx.x;
  if (i >= ET) return;
  int dst = (i < NEDGES) ? ei[NEDGES + i] : (i - NEDGES);
  atomicAdd(&deg[dst], 1);
}

__global__ void k_scan1(const int* __restrict__ deg, int* __restrict__ part,
                        int* __restrict__ bsum, int n) {
  __shared__ int s[256];
  int tid = threadIdx.x;
  int i = blockIdx.x * 256 + tid;
  int v = (i < n) ? deg[i] : 0;
  s[tid] = v;
  __syncthreads();
  for (int off = 1; off < 256; off <<= 1) {
    int t = (tid >= off) ? s[tid - off] : 0;
    __syncthreads();
    s[tid] += t;
    __syncthreads();
  }
  if (i < n) part[i] = s[tid] - v;
  if (tid == 255) bsum[blockIdx.x] = s[255];
}

__global__ void k_scan2(int* bsum, int nb) {
  __shared__ int s[256];
  int t = threadIdx.x;
  int v = (t < nb) ? bsum[t] : 0;
  s[t] = v;
  __syncthreads();
  for (int off = 1; off < 256; off <<= 1) {
    int tv = (t >= off) ? s[t - off] : 0;
    __syncthreads();
    s[t] += tv;
    __syncthreads();
  }
  if (t < nb) bsum[t] = s[t] - v;
}

__global__ void k_scan3(const int* __restrict__ part, const int* __restrict__ bsum,
                        int* __restrict__ rowstart, int* __restrict__ cursor,
                        int n, int total) {
  int i = blockIdx.x * blockDim.x + threadIdx.x;
  if (i < n) {
    int v = part[i] + bsum[i >> 8];
    rowstart[i] = v;
    cursor[i] = v;
  }
  if (i == n) rowstart[n] = total;
}

__global__ void k_scatter(const int* __restrict__ ei, int* __restrict__ cursor,
                          int* __restrict__ csrsrc) {
  int i = blockIdx.x * blockDim.x + threadIdx.x;
  if (i >= ET) return;
  int src, dst;
  if (i < NEDGES) { src = ei[i]; dst = ei[NEDGES + i]; }
  else            { src = dst = i - NEDGES; }
  int pos = atomicAdd(&cursor[dst], 1);
  csrsrc[pos] = src;
}

// ---------------- casts ----------------

__global__ void k_cast_bf16(const float* __restrict__ in, unsigned short* __restrict__ out, int n4) {
  int i = blockIdx.x * blockDim.x + threadIdx.x;
  if (i >= n4) return;
  float4 v = ((const float4*)in)[i];
  ushort4 o;
  o.x = f2bf(v.x); o.y = f2bf(v.y); o.z = f2bf(v.z); o.w = f2bf(v.w);
  ((ushort4*)out)[i] = o;
}

// transpose-cast via 32x32 LDS tiles: W[K][N] f32 -> T[(n+noff)][K] bf16.
__global__ __launch_bounds__(256) void k_castw_all(
    const float* __restrict__ W1l, const float* __restrict__ W1r,
    const float* __restrict__ W2l, const float* __restrict__ W2r,
    unsigned short* __restrict__ w1t, unsigned short* __restrict__ w2t) {
  __shared__ float tile[32][33];
  int which = blockIdx.y;
  const float* W;
  unsigned short* T;
  int K, N, noff;
  if (which == 0)      { W = W1l; T = w1t; K = 512; N = 256; noff = 0; }
  else if (which == 1) { W = W1r; T = w1t; K = 512; N = 256; noff = 256; }
  else if (which == 2) { W = W2l; T = w2t; K = 256; N = 512; noff = 0; }
  else                 { W = W2r; T = w2t; K = 256; N = 512; noff = 512; }
  int tpr = N >> 5;
  int tk = (blockIdx.x / tpr) << 5;
  int tn = (blockIdx.x % tpr) << 5;
  int c = threadIdx.x & 31, r = threadIdx.x >> 5;
#pragma unroll
  for (int rr = 0; rr < 32; rr += 8)
    tile[r + rr][c] = W[(size_t)(tk + r + rr) * N + tn + c];
  __syncthreads();
#pragma unroll
  for (int rr = 0; rr < 32; rr += 8)
    T[(size_t)(tn + r + rr + noff) * K + tk + c] = f2bf(tile[c][r + rr]);
}

// ---------------- bf16 MFMA GEMM, 3-buffer counted-vmcnt pipeline (T4) ----------

template <int N> __device__ __forceinline__ void waitvm() {
  if constexpr (N == 0) asm volatile("s_waitcnt vmcnt(0)" ::: "memory");
  else if constexpr (N == 4) asm volatile("s_waitcnt vmcnt(4)" ::: "memory");
  else asm volatile("s_waitcnt vmcnt(8)" ::: "memory");
}

__global__ __launch_bounds__(256) void k_gemm(
    const unsigned short* __restrict__ A, const unsigned short* __restrict__ Bt,
    const float* __restrict__ bL, const float* __restrict__ bR, int nsplit,
    unsigned short* __restrict__ C, int M, int K, int N) {
  __shared__ unsigned short As[3][128 * 32];   // 3 x 8 KB
  __shared__ unsigned short Bs[3][128 * 32];
  int tid = threadIdx.x;
  int lane = tid & 63, wave = tid >> 6;
  int wr = (wave >> 1) * 64, wc = (wave & 1) * 64;
  int row0 = blockIdx.x * 128, col0 = blockIdx.y * 128;
  int fr = lane & 15, fq = lane >> 4;
  int sr = tid >> 2, sc = (tid & 3) * 8;

  const unsigned short* ga0 = &A[(size_t)(row0 + sr) * K + sc];
  const unsigned short* ga1 = &A[(size_t)(row0 + sr + 64) * K + sc];
  const unsigned short* gb0 = &Bt[(size_t)(col0 + sr) * K + sc];
  const unsigned short* gb1 = &Bt[(size_t)(col0 + sr + 64) * K + sc];

  f32x4 acc[4][4] = {};
  const int NT = K >> 5;   // 16 or 8

#define STAGE(b, k0)                                  \
  do {                                                \
    GLOAD16(ga0 + (k0), &As[b][tid * 8]);             \
    GLOAD16(ga1 + (k0), &As[b][2048 + tid * 8]);      \
    GLOAD16(gb0 + (k0), &Bs[b][tid * 8]);             \
    GLOAD16(gb1 + (k0), &Bs[b][2048 + tid * 8]);      \
  } while (0)

#define COMPUTE(b)                                                        \
  do {                                                                    \
    bf16x8 af[4], bfr[4];                                                 \
    _Pragma("unroll")                                                     \
    for (int m = 0; m < 4; ++m)                                           \
      af[m] = *(const bf16x8*)&As[b][(wr + m * 16 + fr) * 32 + fq * 8];   \
    _Pragma("unroll")                                                     \
    for (int n = 0; n < 4; ++n)                                           \
      bfr[n] = *(const bf16x8*)&Bs[b][(wc + n * 16 + fr) * 32 + fq * 8];  \
    _Pragma("unroll")                                                     \
    for (int m = 0; m < 4; ++m)                                           \
      _Pragma("unroll")                                                   \
      for (int n = 0; n < 4; ++n)                                         \
        acc[m][n] = __builtin_amdgcn_mfma_f32_16x16x32_bf16(af[m], bfr[n], acc[m][n], 0, 0, 0); \
  } while (0)

  STAGE(0, 0);
  STAGE(1, 32);
  STAGE(2, 64);

  for (int t = 0; t < NT - 3; ++t) {
    int b = t % 3;
    waitvm<8>();
    __builtin_amdgcn_s_barrier();
    COMPUTE(b);
    asm volatile("s_waitcnt lgkmcnt(0)" ::: "memory");
    __builtin_amdgcn_sched_barrier(0);
    __builtin_amdgcn_s_barrier();
    STAGE(b, (t + 3) << 5);
  }
  waitvm<8>(); __builtin_amdgcn_s_barrier(); COMPUTE((NT - 3) % 3);
  waitvm<4>(); __builtin_amdgcn_s_barrier(); COMPUTE((NT - 2) % 3);
  waitvm<0>(); __builtin_amdgcn_s_barrier(); COMPUTE((NT - 1) % 3);

#undef STAGE
#undef COMPUTE

#pragma unroll
  for (int m = 0; m < 4; ++m) {
#pragma unroll
    for (int n = 0; n < 4; ++n) {
      int col = col0 + wc + n * 16 + fr;
      float bv = (col < nsplit) ? bL[col] : bR[col - nsplit];
#pragma unroll
      for (int j = 0; j < 4; ++j) {
        int row = row0 + wr + m * 16 + fq * 4 + j;
        if (row < M) C[(size_t)row * N + col] = f2bf(acc[m][n][j] + bv);
      }
    }
  }
}

// ---------------- fused score + softmax + aggregate (bf16 inputs) ----------------
// R13 structure (sequential 4-edge unroll, low VGPR) + packed-f32 math:
// v_pk_add/v_pk_max/v_pk_fma do 2 channels per instruction (the 157 TF rate).
// One wave per dst; 16 lanes/head; lane covers CHL=CQ*4 contiguous channels.
// exp2-domain softmax, no max tracking (|p|<~15 by construction).

template <int CQ> struct raw_t;
template <> struct raw_t<1> { using T = uint2; };
template <> struct raw_t<2> { using T = uint4; };

template <int CQ>
__device__ __forceinline__ void rawwords(const typename raw_t<CQ>::T& r, unsigned* u) {
  u[0] = r.x; u[1] = r.y;
  if constexpr (CQ == 2) { u[2] = r.z; u[3] = r.w; }
}

// unpack raw words into P f32-pairs
template <int CQ>
__device__ __forceinline__ void unpackP(const typename raw_t<CQ>::T& r, f32x2v* x) {
  unsigned u[4];
  rawwords<CQ>(r, u);
#pragma unroll
  for (int j = 0; j < CQ * 2; ++j) x[j] = cvtpair(u[j]);
}

// score partial: sum att2[j] * max(s, 0.2s), packed
template <int CQ>
__device__ __forceinline__ float edge_score_pk(const f32x2v* x, const f32x2v* xr2,
                                               const f32x2v* att2) {
  const f32x2v c02 = {0.2f, 0.2f};
  f32x2v p2 = {0.f, 0.f};
#pragma unroll
  for (int j = 0; j < CQ * 2; ++j) {
    f32x2v s = x[j] + xr2[j];           // v_pk_add_f32
    f32x2v g = VMAX(s, s * c02);        // v_pk_mul + v_pk_max
    p2 = VFMA(att2[j], g, p2);          // v_pk_fma_f32
  }
  return p2.x + p2.y;
}

template <int CQ, int MODE, int STR>
__global__ __launch_bounds__(256) void k_fused(
    const int* __restrict__ rowstart, const int* __restrict__ csrsrc,
    const unsigned short* __restrict__ xlr,
    const float* __restrict__ att, const float* __restrict__ bias,
    void* __restrict__ outp) {
  const int C = CQ * 64;
  const int CHL = CQ * 4;
  const int P = CQ * 2;
  using RawT = typename raw_t<CQ>::T;
  int dst = (blockIdx.x * blockDim.x + threadIdx.x) >> 6;
  int lane = threadIdx.x & 63;
  if (dst >= NNODES) return;
  int h = lane >> 4;
  int l = lane & 15;
  const int choff = h * C + l * CHL;

  f32x2v xr2[P], att2[P];
  {
    RawT xrr = *(const RawT*)&xlr[(size_t)dst * STR + STR / 2 + choff];
    unpackP<CQ>(xrr, xr2);
#pragma unroll
    for (int j = 0; j < P; ++j) {
      att2[j].x = att[choff + j * 2 + 0] * 1.44269504f;
      att2[j].y = att[choff + j * 2 + 1] * 1.44269504f;
    }
  }

  int rs = __builtin_amdgcn_readfirstlane(rowstart[dst]);
  int re = __builtin_amdgcn_readfirstlane(rowstart[dst + 1]);

  float den = 0.f;
  f32x2v acc2[P];
#pragma unroll
  for (int j = 0; j < P; ++j) acc2[j] = (f32x2v){0.f, 0.f};

  int i = rs;
  for (; i + 4 <= re; i += 4) {
    int s0 = csrsrc[i + 0];
    int s1 = csrsrc[i + 1];
    int s2 = csrsrc[i + 2];
    int s3 = csrsrc[i + 3];
    RawT r0 = *(const RawT*)&xlr[(unsigned)s0 * (unsigned)STR + choff];
    RawT r1 = *(const RawT*)&xlr[(unsigned)s1 * (unsigned)STR + choff];
    RawT r2 = *(const RawT*)&xlr[(unsigned)s2 * (unsigned)STR + choff];
    RawT r3 = *(const RawT*)&xlr[(unsigned)s3 * (unsigned)STR + choff];
    f32x2v x0[P], x1[P], x2[P], x3[P];
    unpackP<CQ>(r0, x0); unpackP<CQ>(r1, x1);
    unpackP<CQ>(r2, x2); unpackP<CQ>(r3, x3);
    float p0 = edge_score_pk<CQ>(x0, xr2, att2);
    float p1 = edge_score_pk<CQ>(x1, xr2, att2);
    float p2 = edge_score_pk<CQ>(x2, xr2, att2);
    float p3 = edge_score_pk<CQ>(x3, xr2, att2);
#pragma unroll
    for (int d = 1; d <= 8; d <<= 1) {
      p0 += __shfl_xor(p0, d);
      p1 += __shfl_xor(p1, d);
      p2 += __shfl_xor(p2, d);
      p3 += __shfl_xor(p3, d);
    }
    float w0 = EXP2F(p0), w1 = EXP2F(p1), w2 = EXP2F(p2), w3 = EXP2F(p3);
    den += (w0 + w1) + (w2 + w3);
    f32x2v w0v = {w0, w0}, w1v = {w1, w1}, w2v = {w2, w2}, w3v = {w3, w3};
#pragma unroll
    for (int j = 0; j < P; ++j) {
      f32x2v a = acc2[j];
      a = VFMA(w0v, x0[j], a);
      a = VFMA(w1v, x1[j], a);
      a = VFMA(w2v, x2[j], a);
      a = VFMA(w3v, x3[j], a);
      acc2[j] = a;
    }
  }
  for (; i < re; ++i) {
    int s0 = csrsrc[i];
    RawT r0 = *(const RawT*)&xlr[(unsigned)s0 * (unsigned)STR + choff];
    f32x2v x0[P];
    unpackP<CQ>(r0, x0);
    float p0 = edge_score_pk<CQ>(x0, xr2, att2);
#pragma unroll
    for (int d = 1; d <= 8; d <<= 1) p0 += __shfl_xor(p0, d);
    float w0 = EXP2F(p0);
    den += w0;
    f32x2v wv = {w0, w0};
#pragma unroll
    for (int j = 0; j < P; ++j) acc2[j] = VFMA(wv, x0[j], acc2[j]);
  }

  float inv = 1.f / (den + 1e-16f);

  if (MODE == 0) {
    unsigned short* out = (unsigned short*)outp;
#pragma unroll
    for (int q = 0; q < CQ; ++q) {
      const float4 bv = *(const float4*)&bias[choff + q * 4];
      ushort4 o;
      o.x = f2bf(fmaxf(acc2[q * 2 + 0].x * inv + bv.x, 0.f));
      o.y = f2bf(fmaxf(acc2[q * 2 + 0].y * inv + bv.y, 0.f));
      o.z = f2bf(fmaxf(acc2[q * 2 + 1].x * inv + bv.z, 0.f));
      o.w = f2bf(fmaxf(acc2[q * 2 + 1].y * inv + bv.w, 0.f));
      *(ushort4*)&out[(size_t)dst * (HEADS * C) + choff + q * 4] = o;
    }
  } else {
    float* out = (float*)outp;
    float rr[8];   // CHL <= 8
#pragma unroll
    for (int j = 0; j < P; ++j) {
      rr[j * 2 + 0] = acc2[j].x * inv;
      rr[j * 2 + 1] = acc2[j].y * inv;
    }
#pragma unroll
    for (int c = 0; c < CHL; ++c) {
      rr[c] += __shfl_xor(rr[c], 16);   // sum across heads
      rr[c] += __shfl_xor(rr[c], 32);
    }
    if (lane < 16) {
#pragma unroll
      for (int q = 0; q < CQ; ++q) {
        int c = lane * CHL + q * 4;
        float4 o;
        o.x = rr[q * 4 + 0] * 0.25f + bias[c + 0];
        o.y = rr[q * 4 + 1] * 0.25f + bias[c + 1];
        o.z = rr[q * 4 + 2] * 0.25f + bias[c + 2];
        o.w = rr[q * 4 + 3] * 0.25f + bias[c + 3];
        *(float4*)&out[(size_t)dst * C + c] = o;
      }
    }
  }
}

// ---------------- orchestration ----------------

extern "C" void kernel_launch(void* const* d_in, const int* in_sizes, int n_in,
                              void* d_out, int out_size, void* d_ws, size_t ws_size,
                              hipStream_t stream) {
  (void)in_sizes; (void)n_in; (void)out_size; (void)ws_size;
  const float* x     = (const float*)d_in[0];
  const int*   ei    = (const int*)d_in[1];
  const float* W1l   = (const float*)d_in[2];
  const float* b1l   = (const float*)d_in[3];
  const float* W1r   = (const float*)d_in[4];
  const float* b1r   = (const float*)d_in[5];
  const float* att1  = (const float*)d_in[6];
  const float* bias1 = (const float*)d_in[7];
  const float* W2l   = (const float*)d_in[8];
  const float* b2l   = (const float*)d_in[9];
  const float* W2r   = (const float*)d_in[10];
  const float* b2r   = (const float*)d_in[11];
  const float* att2  = (const float*)d_in[12];
  const float* bias2 = (const float*)d_in[13];
  float* out = (float*)d_out;

  char* ws = (char*)d_ws;
  size_t off = 0;
  auto alloc = [&](size_t bytes) {
    char* p = ws + off;
    off = (off + bytes + 255) & ~(size_t)255;
    return p;
  };
  int*  deg      = (int*)alloc((size_t)NNODES * 4);
  int*  part     = (int*)alloc((size_t)NNODES * 4);
  int*  bsum     = (int*)alloc(256 * 4);
  int*  rowstart = (int*)alloc((size_t)(NNODES + 1) * 4);
  int*  cursor   = (int*)alloc((size_t)NNODES * 4);
  int*  csrsrc   = (int*)alloc((size_t)ET * 4);
  unsigned short* xb   = (unsigned short*)alloc((size_t)NNODES * 512 * 2);
  unsigned short* w1t  = (unsigned short*)alloc((size_t)512 * 512 * 2);
  unsigned short* w2t  = (unsigned short*)alloc((size_t)1024 * 256 * 2);
  unsigned short* xlr1 = (unsigned short*)alloc((size_t)NNODES * 512 * 2);
  unsigned short* hbuf = (unsigned short*)alloc((size_t)NNODES * 256 * 2);
  unsigned short* xlr2 = (unsigned short*)alloc((size_t)NNODES * 1024 * 2);
  (void)alloc(64 * 1024);   // tail pad for GEMM A-row overrun reads

  // CSR build
  (void)hipMemsetAsync(deg, 0, (size_t)NNODES * 4, stream);
  k_hist<<<(ET + 255) / 256, 256, 0, stream>>>(ei, deg);
  int nb = (NNODES + 255) / 256;
  k_scan1<<<nb, 256, 0, stream>>>(deg, part, bsum, NNODES);
  k_scan2<<<1, 256, 0, stream>>>(bsum, nb);
  k_scan3<<<(NNODES + 256) / 256, 256, 0, stream>>>(part, bsum, rowstart, cursor, NNODES, ET);
  k_scatter<<<(ET + 255) / 256, 256, 0, stream>>>(ei, cursor, csrsrc);

  // casts
  k_cast_bf16<<<(NNODES * 512 / 4 + 255) / 256, 256, 0, stream>>>(x, xb, NNODES * 512 / 4);
  k_castw_all<<<dim3(128, 4), 256, 0, stream>>>(W1l, W1r, W2l, W2r, w1t, w2t);

  const int gridM = (NNODES + 127) / 128;   // 391
  const int gridFused = (NNODES + 3) / 4;   // 4 waves/block

  // Layer 1: combined [W1l|W1r], K=512, N=512
  k_gemm<<<dim3(gridM, 4), 256, 0, stream>>>(xb, w1t, b1l, b1r, 256, xlr1, NNODES, 512, 512);
  k_fused<1, 0, 512><<<gridFused, 256, 0, stream>>>(rowstart, csrsrc, xlr1, att1, bias1, hbuf);

  // Layer 2: combined [W2l|W2r], K=256, N=1024
  k_gemm<<<dim3(gridM, 8), 256, 0, stream>>>(hbuf, w2t, b2l, b2r, 512, xlr2, NNODES, 256, 1024);
  k_fused<2, 1, 1024><<<gridFused, 256, 0, stream>>>(rowstart, csrsrc, xlr2, att2, bias2, out);
}